// Round 19
// baseline (136.781 us; speedup 1.0000x reference)
//
#include <hip/hip_runtime.h>
#include <hip/hip_bf16.h>
#include <stdint.h>

typedef __attribute__((ext_vector_type(4))) float f32x4;
typedef __attribute__((ext_vector_type(16))) float f32x16;
typedef __attribute__((ext_vector_type(8))) short short8;

#define DEV __device__ __forceinline__

DEV unsigned short f2bf(float f){
  unsigned u = __float_as_uint(f);
  u += 0x7FFFu + ((u >> 16) & 1u);
  return (unsigned short)(u >> 16);
}
// branch-free erf, Abramowitz-Stegun 7.1.26, |err| <= 1.5e-7
DEV float erf_fast(float x){
  float ax = fabsf(x);
  float t = 1.0f / (1.0f + 0.3275911f * ax);
  float p = t * (0.254829592f + t * (-0.284496736f + t * (1.421413741f +
            t * (-1.453152027f + t * 1.061405429f))));
  float r = 1.0f - p * __expf(-ax * ax);
  return copysignf(r, x);
}
DEV float gelu_exact(float x){ return 0.5f * x * (1.0f + erf_fast(x * 0.70710678118654752f)); }

DEV float exp2_fast(float x){
#if __has_builtin(__builtin_amdgcn_exp2f)
  return __builtin_amdgcn_exp2f(x);
#else
  return exp2f(x);
#endif
}

DEV void gl_lds16(const void* g, void* l){
  __builtin_amdgcn_global_load_lds((const __attribute__((address_space(1))) unsigned int*)g,
                                   (__attribute__((address_space(3))) unsigned int*)l, 16, 0, 0);
}

// scale folded into Q: sqrt(1/1024) * log2(e)  -> softmax in exp2 units
#define QSCALE 0.04508422f

// ---------------- conversion fp32 -> bf16 (q,k,v + 4 weights) + fused rope table ----------------
struct ConvArgs { const float* src[7]; unsigned short* dst[7]; int n[7]; float2* rtab; };

__global__ __launch_bounds__(256) void conv_kernel(ConvArgs a){
  int t = blockIdx.y;
  if (t == 7){ // rope table: cos/sin [2048][32]
    int g = blockIdx.x * 256 + threadIdx.x;
    if (g >= 2048 * 32) return;
    int s = g >> 5, j = g & 31;
    float theta = (float)exp(-(double)j * (9.210340371976184 / 32.0));
    double ang = (double)s * (double)theta;
    a.rtab[g] = make_float2((float)cos(ang), (float)sin(ang));
    return;
  }
  int i = (blockIdx.x * 256 + threadIdx.x) * 4;
  if (i >= a.n[t]) return;
  float4 v = *(const float4*)(a.src[t] + i);
  ushort4 o;
  o.x = f2bf(v.x); o.y = f2bf(v.y); o.z = f2bf(v.z); o.w = f2bf(v.w);
  *(ushort4*)(a.dst[t] + i) = o;
}

// ---------------- fused QKV GEMM: 128x64 tile, 6 blocks/CU ----------------
__global__ __launch_bounds__(256, 6)
void gemm_qkv(const unsigned short* __restrict__ Xq, const unsigned short* __restrict__ Xk, const unsigned short* __restrict__ Xv,
              const unsigned short* __restrict__ Wqb, const unsigned short* __restrict__ Wkb, const unsigned short* __restrict__ Wvb,
              const float* __restrict__ bq, const float* __restrict__ bk, const float* __restrict__ bv,
              unsigned short* __restrict__ Qg, unsigned short* __restrict__ Kg, unsigned short* __restrict__ Vtb,
              const float2* __restrict__ rtab)
{
  __shared__ __align__(16) char lds_raw[24576];
  const int z = blockIdx.z;
  const unsigned short* A = z == 0 ? Xq : z == 1 ? Xk : Xv;
  const unsigned short* W = z == 0 ? Wqb : z == 1 ? Wkb : Wvb;
  const float* bias = z == 0 ? bq : z == 1 ? bk : bv;
  unsigned short* outB = z == 0 ? Qg : z == 1 ? Kg : Vtb;

  const int tid = threadIdx.x, lane = tid & 63, wid = tid >> 6;
  const int m0 = blockIdx.x * 128, n0 = blockIdx.y * 64;

  f32x4 acc[2][4];
#pragma unroll
  for (int i = 0; i < 2; i++)
#pragma unroll
    for (int j = 0; j < 4; j++)
#pragma unroll
      for (int r = 0; r < 4; r++) acc[i][j][r] = 0.0f;

  const int srow = wid * 8 + (lane >> 3);
  const int scc  = ((lane & 7) ^ (lane >> 3)) * 8;
  const int rxor = lane & 7;

  unsigned short* Als = (unsigned short*)lds_raw;        // [128][64]
  unsigned short* Bls = Als + 8192;                      // [64][64]

  for (int kt = 0; kt < 16; ++kt){
    int kk = kt * 64;
    __syncthreads();
#pragma unroll
    for (int t = 0; t < 4; t++)
      gl_lds16(A + (size_t)(m0 + t * 32 + srow) * 1024 + kk + scc,
               lds_raw + (t * 2048 + wid * 512) * 2);
#pragma unroll
    for (int t = 0; t < 2; t++)
      gl_lds16(W + (size_t)(n0 + t * 32 + srow) * 1024 + kk + scc,
               lds_raw + 16384 + (t * 2048 + wid * 512) * 2);
    __syncthreads();
#pragma unroll
    for (int dk = 0; dk < 2; ++dk){
      short8 af[2], bfr[4];
      int cidx = (((dk * 4 + (lane >> 4)) ^ rxor) << 3);
#pragma unroll
      for (int i = 0; i < 2; i++)
        af[i] = *(const short8*)(Als + (wid * 32 + i * 16 + (lane & 15)) * 64 + cidx);
#pragma unroll
      for (int j = 0; j < 4; j++)
        bfr[j] = *(const short8*)(Bls + (j * 16 + (lane & 15)) * 64 + cidx);
#pragma unroll
      for (int i = 0; i < 2; i++)
#pragma unroll
        for (int j = 0; j < 4; j++)
          acc[i][j] = __builtin_amdgcn_mfma_f32_16x16x32_bf16(af[i], bfr[j], acc[i][j], 0, 0, 0);
    }
  }
  __syncthreads();

  if (z == 2){ // V transpose: block = one head (hh = n0>>6). Tb per wave [64 d][34]
    const int hh = n0 >> 6;
    unsigned short* Tb = (unsigned short*)lds_raw + wid * 2176;
#pragma unroll
    for (int i = 0; i < 2; i++)
#pragma unroll
      for (int j = 0; j < 4; j++){
        int d = j * 16 + (lane & 15);
        float b = bias[n0 + d];
#pragma unroll
        for (int r = 0; r < 4; r++){
          int lm = i * 16 + (lane >> 4) * 4 + r;
          Tb[d * 34 + lm] = f2bf(gelu_exact(acc[i][j][r] + b));
        }
      }
    __syncthreads();
    int mbase = m0 + wid * 32;
    int i0 = ((mbase >> 11) << 10) + ((mbase & 2047) >> 1);
    int d = lane;
#pragma unroll
    for (int p = 0; p < 2; p++){
      unsigned short* dst = outB + ((size_t)((hh + (p << 4)) * 64 + d)) * 2048 + i0;
#pragma unroll
      for (int g = 0; g < 4; g++){
        ushort4 pk;
        pk.x = Tb[d * 34 + p + (g * 4 + 0) * 2];
        pk.y = Tb[d * 34 + p + (g * 4 + 1) * 2];
        pk.z = Tb[d * 34 + p + (g * 4 + 2) * 2];
        pk.w = Tb[d * 34 + p + (g * 4 + 3) * 2];
        *(ushort4*)(dst + g * 4) = pk;
      }
    }
  } else { // rope + scatter
    float scale = (z == 0) ? QSCALE : 1.0f;
#pragma unroll
    for (int i = 0; i < 2; i++)
#pragma unroll
      for (int j = 0; j < 4; j++){
        int n = n0 + j * 16 + (lane & 15);
        float b = bias[n];
#pragma unroll
        for (int r = 0; r < 4; r++){
          int m = m0 + wid * 32 + i * 16 + (lane >> 4) * 4 + r;
          float val = gelu_exact(acc[i][j][r] + b);
          float pv = __shfl_xor(val, 1);
          int st = m & 2047;
          float2 cs = rtab[st * 32 + ((n >> 1) & 31)];
          float out = ((n & 1) == 0) ? (val * cs.x - pv * cs.y) : (val * cs.x + pv * cs.y);
          out *= scale;
          int nh = ((n >> 6) & 15) + ((st & 1) << 4);
          int ii = ((m >> 11) << 10) + (st >> 1);
          outB[(nh * 2048 + ii) * 64 + (n & 63)] = f2bf(out);
        }
      }
  }
}

// ---------------- final GEMM: 64x64 tile, 4 blocks/CU ----------------
__global__ __launch_bounds__(256, 4)
void gemm_o(const unsigned short* __restrict__ aOg, const unsigned short* __restrict__ W,
            const float* __restrict__ bias, float* __restrict__ outF)
{
  __shared__ __align__(16) char lds_raw[16384];
  const int tid = threadIdx.x, lane = tid & 63, wid = tid >> 6;
  const int m0 = blockIdx.x * 64, n0 = blockIdx.y * 64;

  f32x4 acc[4];
#pragma unroll
  for (int j = 0; j < 4; j++)
#pragma unroll
    for (int r = 0; r < 4; r++) acc[j][r] = 0.0f;

  const int srow = wid * 8 + (lane >> 3);
  const int scc  = ((lane & 7) ^ (lane >> 3)) * 8;
  const int rxor = lane & 7;

  unsigned short* Als = (unsigned short*)lds_raw;   // [64][64]
  unsigned short* Bls = Als + 4096;                 // [64][64]

  for (int kt = 0; kt < 16; ++kt){
    int kk = kt * 64;
    __syncthreads();
#pragma unroll
    for (int t = 0; t < 2; t++){
      int row = m0 + t * 32 + srow;
      int nn = kt + ((row & 1) << 4);
      int iq = ((row >> 11) << 10) + ((row & 2047) >> 1);
      gl_lds16(aOg + ((size_t)nn * 2048 + iq) * 64 + scc,
               lds_raw + (t * 2048 + wid * 512) * 2);
      gl_lds16(W + (size_t)(n0 + t * 32 + srow) * 1024 + kk + scc,
               lds_raw + 8192 + (t * 2048 + wid * 512) * 2);
    }
    __syncthreads();
#pragma unroll
    for (int dk = 0; dk < 2; ++dk){
      short8 af, bfr[4];
      int cidx = (((dk * 4 + (lane >> 4)) ^ rxor) << 3);
      af = *(const short8*)(Als + (wid * 16 + (lane & 15)) * 64 + cidx);
#pragma unroll
      for (int j = 0; j < 4; j++)
        bfr[j] = *(const short8*)(Bls + (j * 16 + (lane & 15)) * 64 + cidx);
#pragma unroll
      for (int j = 0; j < 4; j++)
        acc[j] = __builtin_amdgcn_mfma_f32_16x16x32_bf16(af, bfr[j], acc[j], 0, 0, 0);
    }
  }
#pragma unroll
  for (int j = 0; j < 4; j++){
    int n = n0 + j * 16 + (lane & 15);
    float b = bias[n];
#pragma unroll
    for (int r = 0; r < 4; r++){
      int m = m0 + wid * 16 + (lane >> 4) * 4 + r;
      outF[m * 1024 + n] = gelu_exact(acc[j][r] + b);
    }
  }
}

// ---------------- flash attention: Q-SPLIT (QBLK=64, 2 waves/block, 1024 blocks) ----------------
// Same per-wave structure as R14/R18 (KVBLK=128, single 32KB buffer, 2 barriers/tile),
// but 4 independent barrier domains per CU instead of 2 -> finer cross-block phase
// interleave (m114 mechanism). Costs: 2x staging writes + 2x KV global re-reads (L2).
__global__ __launch_bounds__(128, 2)
void attn_kernel(const unsigned short* __restrict__ Qg,
                 const unsigned short* __restrict__ Kg,
                 const unsigned short* __restrict__ Vt,
                 unsigned short* __restrict__ aOg)
{
  __shared__ __align__(16) char lds_raw[32768];
  unsigned short* Kls = (unsigned short*)lds_raw;            // [128 key][64 d] swz
  unsigned short* Vls = (unsigned short*)(lds_raw + 16384);  // [64 d][128 key] swz
  const int tid = threadIdx.x, lane = tid & 63, wid = tid >> 6;   // wid 0..1
  const int q31 = lane & 31, h = lane >> 5;
  const int bid = blockIdx.x;
  const int n = (bid & 7) * 4 + ((bid >> 3) >> 5);   // 4 groups per XCD
  const int qtile = (bid >> 3) & 31;                  // 32 q-tiles of 64
  const int qbase = qtile * 64;
  const unsigned short* Qn = Qg + (size_t)n * 2048 * 64;
  const unsigned short* Kn = Kg + (size_t)n * 2048 * 64;
  const unsigned short* Vn = Vt + (size_t)n * 64 * 2048;

  short8 qf[4];
  {
    int qrow = qbase + wid * 32 + q31;
#pragma unroll
    for (int c = 0; c < 4; c++)
      qf[c] = *(const short8*)(Qn + qrow * 64 + c * 16 + h * 8);
  }
  f32x16 o0, o1, lsum;
#pragma unroll
  for (int r = 0; r < 16; r++){ o0[r] = 0.0f; o1[r] = 0.0f; lsum[r] = 0.0f; }

  short8 rk[8], rv[8];
#pragma unroll
  for (int t = 0; t < 8; t++){
    int chunk = t * 128 + tid;
    rk[t] = *(const short8*)(Kn + (chunk >> 3) * 64 + (chunk & 7) * 8);
    rv[t] = *(const short8*)(Vn + (size_t)(chunk >> 4) * 2048 + (chunk & 15) * 8);
  }

  for (int kb = 0; kb < 2048; kb += 128){
    __syncthreads();
#pragma unroll
    for (int t = 0; t < 8; t++){
      int chunk = t * 128 + tid;
      { int row = chunk >> 3, c = chunk & 7;
        *(short8*)(Kls + row * 64 + ((c ^ (row & 7)) << 3)) = rk[t]; }
      { int row = chunk >> 4, c = chunk & 15;
        *(short8*)(Vls + row * 128 + ((c ^ (row & 7)) << 3)) = rv[t]; }
    }
    __syncthreads();
    if (kb + 128 < 2048){
#pragma unroll
      for (int t = 0; t < 8; t++){
        int chunk = t * 128 + tid;
        rk[t] = *(const short8*)(Kn + (kb + 128 + (chunk >> 3)) * 64 + (chunk & 7) * 8);
        rv[t] = *(const short8*)(Vn + (size_t)(chunk >> 4) * 2048 + kb + 128 + (chunk & 15) * 8);
      }
    }
    f32x16 s[4];
#pragma unroll
    for (int g = 0; g < 4; g++)
#pragma unroll
      for (int r = 0; r < 16; r++) s[g][r] = 0.0f;
    __builtin_amdgcn_s_setprio(1);
#pragma unroll
    for (int c = 0; c < 4; c++){
      int sl = (c << 1) | h;
#pragma unroll
      for (int g = 0; g < 4; g++){
        int row = g * 32 + q31;
        short8 kf = *(const short8*)(Kls + row * 64 + ((sl ^ (row & 7)) << 3));
        s[g] = __builtin_amdgcn_mfma_f32_32x32x16_bf16(kf, qf[c], s[g], 0, 0, 0);
      }
    }
    __builtin_amdgcn_s_setprio(0);
#pragma unroll
    for (int g = 0; g < 4; g++){
#pragma unroll
      for (int r = 0; r < 16; r++) s[g][r] = exp2_fast(s[g][r]);
      lsum += s[g];
    }
    __builtin_amdgcn_s_setprio(1);
#pragma unroll
    for (int kc = 0; kc < 8; kc++){
      const f32x16& S = s[kc >> 1];
      const int rb = (kc & 1) * 8;
      unsigned a0, a1, b0, b1;
      asm("v_cvt_pk_bf16_f32 %0, %1, %2" : "=v"(a0) : "v"(S[rb + 0]), "v"(S[rb + 1]));
      asm("v_cvt_pk_bf16_f32 %0, %1, %2" : "=v"(a1) : "v"(S[rb + 2]), "v"(S[rb + 3]));
      asm("v_cvt_pk_bf16_f32 %0, %1, %2" : "=v"(b0) : "v"(S[rb + 4]), "v"(S[rb + 5]));
      asm("v_cvt_pk_bf16_f32 %0, %1, %2" : "=v"(b1) : "v"(S[rb + 6]), "v"(S[rb + 7]));
      asm("v_permlane32_swap_b32 %0, %1" : "+v"(a0), "+v"(b0));
      asm("v_permlane32_swap_b32 %0, %1" : "+v"(a1), "+v"(b1));
      union { int i[4]; short8 s; } u;
      u.i[0] = (int)a0; u.i[1] = (int)a1; u.i[2] = (int)b0; u.i[3] = (int)b1;
      short8 pf = u.s;
      int sl = (kc << 1) | h;
      {
        short8 vf = *(const short8*)(Vls + q31 * 128 + ((sl ^ (q31 & 7)) << 3));
        o0 = __builtin_amdgcn_mfma_f32_32x32x16_bf16(vf, pf, o0, 0, 0, 0);
      }
      {
        int dr = 32 + q31;
        short8 vf = *(const short8*)(Vls + dr * 128 + ((sl ^ (dr & 7)) << 3));
        o1 = __builtin_amdgcn_mfma_f32_32x32x16_bf16(vf, pf, o1, 0, 0, 0);
      }
    }
    __builtin_amdgcn_s_setprio(0);
  }
  float l = 0.0f;
#pragma unroll
  for (int r = 0; r < 16; r++) l += lsum[r];
  l += __shfl_xor(l, 32);
  float rl = 1.0f / l;
  const int iq = qbase + wid * 32 + q31;
  unsigned short* dst = aOg + ((size_t)n * 2048 + iq) * 64;
  // packed epilogue: rows r=4rr..4rr+3 map to consecutive dl = 8rr+4h+j -> ushort4 stores
#pragma unroll
  for (int rr = 0; rr < 4; rr++){
    ushort4 p0, p1;
    p0.x = f2bf(o0[rr * 4 + 0] * rl); p0.y = f2bf(o0[rr * 4 + 1] * rl);
    p0.z = f2bf(o0[rr * 4 + 2] * rl); p0.w = f2bf(o0[rr * 4 + 3] * rl);
    p1.x = f2bf(o1[rr * 4 + 0] * rl); p1.y = f2bf(o1[rr * 4 + 1] * rl);
    p1.z = f2bf(o1[rr * 4 + 2] * rl); p1.w = f2bf(o1[rr * 4 + 3] * rl);
    *(ushort4*)(dst + rr * 8 + 4 * h)      = p0;
    *(ushort4*)(dst + 32 + rr * 8 + 4 * h) = p1;
  }
}

// ---------------- launch ----------------
extern "C" void kernel_launch(void* const* d_in, const int* in_sizes, int n_in,
                              void* d_out, int out_size, void* d_ws, size_t ws_size,
                              hipStream_t stream)
{
  const float* q  = (const float*)d_in[0];
  const float* k  = (const float*)d_in[1];
  const float* v  = (const float*)d_in[2];
  const float* Wq = (const float*)d_in[3];
  const float* bq = (const float*)d_in[4];
  const float* Wk = (const float*)d_in[5];
  const float* bk = (const float*)d_in[6];
  const float* Wv = (const float*)d_in[7];
  const float* bv = (const float*)d_in[8];
  const float* Wo = (const float*)d_in[9];
  const float* bo = (const float*)d_in[10];

  char* ws = (char*)d_ws;
  size_t off = 0;
  auto alloc = [&](size_t bytes) -> void* {
    void* p = ws + off;
    off += (bytes + 255) & ~(size_t)255;
    return p;
  };
  unsigned short* Xq  = (unsigned short*)alloc(4194304ull * 2);
  unsigned short* Xk  = (unsigned short*)alloc(4194304ull * 2);
  unsigned short* Xv  = (unsigned short*)alloc(4194304ull * 2);
  unsigned short* Wqb = (unsigned short*)alloc(1048576ull * 2);
  unsigned short* Wkb = (unsigned short*)alloc(1048576ull * 2);
  unsigned short* Wvb = (unsigned short*)alloc(1048576ull * 2);
  unsigned short* Wob = (unsigned short*)alloc(1048576ull * 2);
  unsigned short* Qg  = (unsigned short*)alloc(4194304ull * 2);
  unsigned short* Kg  = (unsigned short*)alloc(4194304ull * 2);
  unsigned short* Vtb = (unsigned short*)alloc(4194304ull * 2);
  unsigned short* aOg = (unsigned short*)alloc(4194304ull * 2);
  float2*         rtab = (float2*)alloc(2048ull * 32 * 8);

  ConvArgs ca;
  const float* srcs[7] = {q, k, v, Wq, Wk, Wv, Wo};
  unsigned short* dsts[7] = {Xq, Xk, Xv, Wqb, Wkb, Wvb, Wob};
  int ns[7] = {4194304, 4194304, 4194304, 1048576, 1048576, 1048576, 1048576};
  for (int i = 0; i < 7; i++){ ca.src[i] = srcs[i]; ca.dst[i] = dsts[i]; ca.n[i] = ns[i]; }
  ca.rtab = rtab;

  conv_kernel<<<dim3(4096, 8), 256, 0, stream>>>(ca);
  gemm_qkv<<<dim3(32, 16, 3), 256, 0, stream>>>(Xq, Xk, Xv, Wqb, Wkb, Wvb, bq, bk, bv, Qg, Kg, Vtb, rtab);
  attn_kernel<<<dim3(1024), 128, 0, stream>>>(Qg, Kg, Vtb, aOg);
  gemm_o<<<dim3(64, 16), 256, 0, stream>>>(aOg, Wob, bo, (float*)d_out);
}

// Round 20
// 116.956 us; speedup vs baseline: 1.1695x; 1.1695x over previous
//
#include <hip/hip_runtime.h>
#include <hip/hip_bf16.h>
#include <stdint.h>

typedef __attribute__((ext_vector_type(4))) float f32x4;
typedef __attribute__((ext_vector_type(16))) float f32x16;
typedef __attribute__((ext_vector_type(8))) short short8;

#define DEV __device__ __forceinline__

DEV unsigned short f2bf(float f){
  unsigned u = __float_as_uint(f);
  u += 0x7FFFu + ((u >> 16) & 1u);
  return (unsigned short)(u >> 16);
}
// branch-free erf, Abramowitz-Stegun 7.1.26, |err| <= 1.5e-7
DEV float erf_fast(float x){
  float ax = fabsf(x);
  float t = 1.0f / (1.0f + 0.3275911f * ax);
  float p = t * (0.254829592f + t * (-0.284496736f + t * (1.421413741f +
            t * (-1.453152027f + t * 1.061405429f))));
  float r = 1.0f - p * __expf(-ax * ax);
  return copysignf(r, x);
}
DEV float gelu_exact(float x){ return 0.5f * x * (1.0f + erf_fast(x * 0.70710678118654752f)); }

DEV float exp2_fast(float x){
#if __has_builtin(__builtin_amdgcn_exp2f)
  return __builtin_amdgcn_exp2f(x);
#else
  return exp2f(x);
#endif
}

DEV void gl_lds16(const void* g, void* l){
  __builtin_amdgcn_global_load_lds((const __attribute__((address_space(1))) unsigned int*)g,
                                   (__attribute__((address_space(3))) unsigned int*)l, 16, 0, 0);
}

// scale folded into Q: sqrt(1/1024) * log2(e)  -> softmax in exp2 units
#define QSCALE 0.04508422f

// ---------------- conversion fp32 -> bf16 (q,k,v + 4 weights) + fused rope table ----------------
struct ConvArgs { const float* src[7]; unsigned short* dst[7]; int n[7]; float2* rtab; };

__global__ __launch_bounds__(256) void conv_kernel(ConvArgs a){
  int t = blockIdx.y;
  if (t == 7){ // rope table: cos/sin [2048][32]
    int g = blockIdx.x * 256 + threadIdx.x;
    if (g >= 2048 * 32) return;
    int s = g >> 5, j = g & 31;
    float theta = (float)exp(-(double)j * (9.210340371976184 / 32.0));
    double ang = (double)s * (double)theta;
    a.rtab[g] = make_float2((float)cos(ang), (float)sin(ang));
    return;
  }
  int i = (blockIdx.x * 256 + threadIdx.x) * 4;
  if (i >= a.n[t]) return;
  float4 v = *(const float4*)(a.src[t] + i);
  ushort4 o;
  o.x = f2bf(v.x); o.y = f2bf(v.y); o.z = f2bf(v.z); o.w = f2bf(v.w);
  *(ushort4*)(a.dst[t] + i) = o;
}

// ---------------- fused QKV GEMM: 128x64 tile, 6 blocks/CU ----------------
__global__ __launch_bounds__(256, 6)
void gemm_qkv(const unsigned short* __restrict__ Xq, const unsigned short* __restrict__ Xk, const unsigned short* __restrict__ Xv,
              const unsigned short* __restrict__ Wqb, const unsigned short* __restrict__ Wkb, const unsigned short* __restrict__ Wvb,
              const float* __restrict__ bq, const float* __restrict__ bk, const float* __restrict__ bv,
              unsigned short* __restrict__ Qg, unsigned short* __restrict__ Kg, unsigned short* __restrict__ Vtb,
              const float2* __restrict__ rtab)
{
  __shared__ __align__(16) char lds_raw[24576];
  const int z = blockIdx.z;
  const unsigned short* A = z == 0 ? Xq : z == 1 ? Xk : Xv;
  const unsigned short* W = z == 0 ? Wqb : z == 1 ? Wkb : Wvb;
  const float* bias = z == 0 ? bq : z == 1 ? bk : bv;
  unsigned short* outB = z == 0 ? Qg : z == 1 ? Kg : Vtb;

  const int tid = threadIdx.x, lane = tid & 63, wid = tid >> 6;
  const int m0 = blockIdx.x * 128, n0 = blockIdx.y * 64;

  f32x4 acc[2][4];
#pragma unroll
  for (int i = 0; i < 2; i++)
#pragma unroll
    for (int j = 0; j < 4; j++)
#pragma unroll
      for (int r = 0; r < 4; r++) acc[i][j][r] = 0.0f;

  const int srow = wid * 8 + (lane >> 3);
  const int scc  = ((lane & 7) ^ (lane >> 3)) * 8;
  const int rxor = lane & 7;

  unsigned short* Als = (unsigned short*)lds_raw;        // [128][64]
  unsigned short* Bls = Als + 8192;                      // [64][64]

  for (int kt = 0; kt < 16; ++kt){
    int kk = kt * 64;
    __syncthreads();
#pragma unroll
    for (int t = 0; t < 4; t++)
      gl_lds16(A + (size_t)(m0 + t * 32 + srow) * 1024 + kk + scc,
               lds_raw + (t * 2048 + wid * 512) * 2);
#pragma unroll
    for (int t = 0; t < 2; t++)
      gl_lds16(W + (size_t)(n0 + t * 32 + srow) * 1024 + kk + scc,
               lds_raw + 16384 + (t * 2048 + wid * 512) * 2);
    __syncthreads();
#pragma unroll
    for (int dk = 0; dk < 2; ++dk){
      short8 af[2], bfr[4];
      int cidx = (((dk * 4 + (lane >> 4)) ^ rxor) << 3);
#pragma unroll
      for (int i = 0; i < 2; i++)
        af[i] = *(const short8*)(Als + (wid * 32 + i * 16 + (lane & 15)) * 64 + cidx);
#pragma unroll
      for (int j = 0; j < 4; j++)
        bfr[j] = *(const short8*)(Bls + (j * 16 + (lane & 15)) * 64 + cidx);
#pragma unroll
      for (int i = 0; i < 2; i++)
#pragma unroll
        for (int j = 0; j < 4; j++)
          acc[i][j] = __builtin_amdgcn_mfma_f32_16x16x32_bf16(af[i], bfr[j], acc[i][j], 0, 0, 0);
    }
  }
  __syncthreads();

  if (z == 2){ // V transpose: block = one head (hh = n0>>6). Tb per wave [64 d][34]
    const int hh = n0 >> 6;
    unsigned short* Tb = (unsigned short*)lds_raw + wid * 2176;
#pragma unroll
    for (int i = 0; i < 2; i++)
#pragma unroll
      for (int j = 0; j < 4; j++){
        int d = j * 16 + (lane & 15);
        float b = bias[n0 + d];
#pragma unroll
        for (int r = 0; r < 4; r++){
          int lm = i * 16 + (lane >> 4) * 4 + r;
          Tb[d * 34 + lm] = f2bf(gelu_exact(acc[i][j][r] + b));
        }
      }
    __syncthreads();
    int mbase = m0 + wid * 32;
    int i0 = ((mbase >> 11) << 10) + ((mbase & 2047) >> 1);
    int d = lane;
#pragma unroll
    for (int p = 0; p < 2; p++){
      unsigned short* dst = outB + ((size_t)((hh + (p << 4)) * 64 + d)) * 2048 + i0;
#pragma unroll
      for (int g = 0; g < 4; g++){
        ushort4 pk;
        pk.x = Tb[d * 34 + p + (g * 4 + 0) * 2];
        pk.y = Tb[d * 34 + p + (g * 4 + 1) * 2];
        pk.z = Tb[d * 34 + p + (g * 4 + 2) * 2];
        pk.w = Tb[d * 34 + p + (g * 4 + 3) * 2];
        *(ushort4*)(dst + g * 4) = pk;
      }
    }
  } else { // rope + scatter
    float scale = (z == 0) ? QSCALE : 1.0f;
#pragma unroll
    for (int i = 0; i < 2; i++)
#pragma unroll
      for (int j = 0; j < 4; j++){
        int n = n0 + j * 16 + (lane & 15);
        float b = bias[n];
#pragma unroll
        for (int r = 0; r < 4; r++){
          int m = m0 + wid * 32 + i * 16 + (lane >> 4) * 4 + r;
          float val = gelu_exact(acc[i][j][r] + b);
          float pv = __shfl_xor(val, 1);
          int st = m & 2047;
          float2 cs = rtab[st * 32 + ((n >> 1) & 31)];
          float out = ((n & 1) == 0) ? (val * cs.x - pv * cs.y) : (val * cs.x + pv * cs.y);
          out *= scale;
          int nh = ((n >> 6) & 15) + ((st & 1) << 4);
          int ii = ((m >> 11) << 10) + (st >> 1);
          outB[(nh * 2048 + ii) * 64 + (n & 63)] = f2bf(out);
        }
      }
  }
}

// ---------------- final GEMM: 64x64 tile, 4 blocks/CU ----------------
__global__ __launch_bounds__(256, 4)
void gemm_o(const unsigned short* __restrict__ aOg, const unsigned short* __restrict__ W,
            const float* __restrict__ bias, float* __restrict__ outF)
{
  __shared__ __align__(16) char lds_raw[16384];
  const int tid = threadIdx.x, lane = tid & 63, wid = tid >> 6;
  const int m0 = blockIdx.x * 64, n0 = blockIdx.y * 64;

  f32x4 acc[4];
#pragma unroll
  for (int j = 0; j < 4; j++)
#pragma unroll
    for (int r = 0; r < 4; r++) acc[j][r] = 0.0f;

  const int srow = wid * 8 + (lane >> 3);
  const int scc  = ((lane & 7) ^ (lane >> 3)) * 8;
  const int rxor = lane & 7;

  unsigned short* Als = (unsigned short*)lds_raw;   // [64][64]
  unsigned short* Bls = Als + 4096;                 // [64][64]

  for (int kt = 0; kt < 16; ++kt){
    int kk = kt * 64;
    __syncthreads();
#pragma unroll
    for (int t = 0; t < 2; t++){
      int row = m0 + t * 32 + srow;
      int nn = kt + ((row & 1) << 4);
      int iq = ((row >> 11) << 10) + ((row & 2047) >> 1);
      gl_lds16(aOg + ((size_t)nn * 2048 + iq) * 64 + scc,
               lds_raw + (t * 2048 + wid * 512) * 2);
      gl_lds16(W + (size_t)(n0 + t * 32 + srow) * 1024 + kk + scc,
               lds_raw + 8192 + (t * 2048 + wid * 512) * 2);
    }
    __syncthreads();
#pragma unroll
    for (int dk = 0; dk < 2; ++dk){
      short8 af, bfr[4];
      int cidx = (((dk * 4 + (lane >> 4)) ^ rxor) << 3);
      af = *(const short8*)(Als + (wid * 16 + (lane & 15)) * 64 + cidx);
#pragma unroll
      for (int j = 0; j < 4; j++)
        bfr[j] = *(const short8*)(Bls + (j * 16 + (lane & 15)) * 64 + cidx);
#pragma unroll
      for (int j = 0; j < 4; j++)
        acc[j] = __builtin_amdgcn_mfma_f32_16x16x32_bf16(af, bfr[j], acc[j], 0, 0, 0);
    }
  }
#pragma unroll
  for (int j = 0; j < 4; j++){
    int n = n0 + j * 16 + (lane & 15);
    float b = bias[n];
#pragma unroll
    for (int r = 0; r < 4; r++){
      int m = m0 + wid * 16 + (lane >> 4) * 4 + r;
      outF[m * 1024 + n] = gelu_exact(acc[j][r] + b);
    }
  }
}

// ---------------- flash attention: R14 structure (KVBLK=128, single buffer), packed stores ----------------
__global__ __launch_bounds__(256, 2)
void attn_kernel(const unsigned short* __restrict__ Qg,
                 const unsigned short* __restrict__ Kg,
                 const unsigned short* __restrict__ Vt,
                 unsigned short* __restrict__ aOg)
{
  __shared__ __align__(16) char lds_raw[32768];
  unsigned short* Kls = (unsigned short*)lds_raw;            // [128 key][64 d] swz
  unsigned short* Vls = (unsigned short*)(lds_raw + 16384);  // [64 d][128 key] swz
  const int tid = threadIdx.x, lane = tid & 63, wid = tid >> 6;
  const int q31 = lane & 31, h = lane >> 5;
  const int bid = blockIdx.x;
  const int n = (bid & 7) * 4 + ((bid >> 3) >> 4);
  const int qtile = (bid >> 3) & 15;
  const int qbase = qtile * 128;
  const unsigned short* Qn = Qg + (size_t)n * 2048 * 64;
  const unsigned short* Kn = Kg + (size_t)n * 2048 * 64;
  const unsigned short* Vn = Vt + (size_t)n * 64 * 2048;

  short8 qf[4];
  {
    int qrow = qbase + wid * 32 + q31;
#pragma unroll
    for (int c = 0; c < 4; c++)
      qf[c] = *(const short8*)(Qn + qrow * 64 + c * 16 + h * 8);
  }
  f32x16 o0, o1, lsum;
#pragma unroll
  for (int r = 0; r < 16; r++){ o0[r] = 0.0f; o1[r] = 0.0f; lsum[r] = 0.0f; }

  short8 rk[4], rv[4];
#pragma unroll
  for (int t = 0; t < 4; t++){
    int chunk = t * 256 + tid;
    rk[t] = *(const short8*)(Kn + (chunk >> 3) * 64 + (chunk & 7) * 8);
    rv[t] = *(const short8*)(Vn + (size_t)(chunk >> 4) * 2048 + (chunk & 15) * 8);
  }

  for (int kb = 0; kb < 2048; kb += 128){
    __syncthreads();
#pragma unroll
    for (int t = 0; t < 4; t++){
      int chunk = t * 256 + tid;
      { int row = chunk >> 3, c = chunk & 7;
        *(short8*)(Kls + row * 64 + ((c ^ (row & 7)) << 3)) = rk[t]; }
      { int row = chunk >> 4, c = chunk & 15;
        *(short8*)(Vls + row * 128 + ((c ^ (row & 7)) << 3)) = rv[t]; }
    }
    __syncthreads();
    if (kb + 128 < 2048){
#pragma unroll
      for (int t = 0; t < 4; t++){
        int chunk = t * 256 + tid;
        rk[t] = *(const short8*)(Kn + (kb + 128 + (chunk >> 3)) * 64 + (chunk & 7) * 8);
        rv[t] = *(const short8*)(Vn + (size_t)(chunk >> 4) * 2048 + kb + 128 + (chunk & 15) * 8);
      }
    }
    f32x16 s[4];
#pragma unroll
    for (int g = 0; g < 4; g++)
#pragma unroll
      for (int r = 0; r < 16; r++) s[g][r] = 0.0f;
    __builtin_amdgcn_s_setprio(1);
#pragma unroll
    for (int c = 0; c < 4; c++){
      int sl = (c << 1) | h;
#pragma unroll
      for (int g = 0; g < 4; g++){
        int row = g * 32 + q31;
        short8 kf = *(const short8*)(Kls + row * 64 + ((sl ^ (row & 7)) << 3));
        s[g] = __builtin_amdgcn_mfma_f32_32x32x16_bf16(kf, qf[c], s[g], 0, 0, 0);
      }
    }
    __builtin_amdgcn_s_setprio(0);
#pragma unroll
    for (int g = 0; g < 4; g++){
#pragma unroll
      for (int r = 0; r < 16; r++) s[g][r] = exp2_fast(s[g][r]);
      lsum += s[g];
    }
    __builtin_amdgcn_s_setprio(1);
#pragma unroll
    for (int kc = 0; kc < 8; kc++){
      const f32x16& S = s[kc >> 1];
      const int rb = (kc & 1) * 8;
      unsigned a0, a1, b0, b1;
      asm("v_cvt_pk_bf16_f32 %0, %1, %2" : "=v"(a0) : "v"(S[rb + 0]), "v"(S[rb + 1]));
      asm("v_cvt_pk_bf16_f32 %0, %1, %2" : "=v"(a1) : "v"(S[rb + 2]), "v"(S[rb + 3]));
      asm("v_cvt_pk_bf16_f32 %0, %1, %2" : "=v"(b0) : "v"(S[rb + 4]), "v"(S[rb + 5]));
      asm("v_cvt_pk_bf16_f32 %0, %1, %2" : "=v"(b1) : "v"(S[rb + 6]), "v"(S[rb + 7]));
      asm("v_permlane32_swap_b32 %0, %1" : "+v"(a0), "+v"(b0));
      asm("v_permlane32_swap_b32 %0, %1" : "+v"(a1), "+v"(b1));
      union { int i[4]; short8 s; } u;
      u.i[0] = (int)a0; u.i[1] = (int)a1; u.i[2] = (int)b0; u.i[3] = (int)b1;
      short8 pf = u.s;
      int sl = (kc << 1) | h;
      {
        short8 vf = *(const short8*)(Vls + q31 * 128 + ((sl ^ (q31 & 7)) << 3));
        o0 = __builtin_amdgcn_mfma_f32_32x32x16_bf16(vf, pf, o0, 0, 0, 0);
      }
      {
        int dr = 32 + q31;
        short8 vf = *(const short8*)(Vls + dr * 128 + ((sl ^ (dr & 7)) << 3));
        o1 = __builtin_amdgcn_mfma_f32_32x32x16_bf16(vf, pf, o1, 0, 0, 0);
      }
    }
    __builtin_amdgcn_s_setprio(0);
  }
  float l = 0.0f;
#pragma unroll
  for (int r = 0; r < 16; r++) l += lsum[r];
  l += __shfl_xor(l, 32);
  float rl = 1.0f / l;
  const int iq = qbase + wid * 32 + q31;
  unsigned short* dst = aOg + ((size_t)n * 2048 + iq) * 64;
  // packed epilogue: rows r=4rr..4rr+3 map to consecutive dl = 8rr+4h+j -> ushort4 stores
#pragma unroll
  for (int rr = 0; rr < 4; rr++){
    ushort4 p0, p1;
    p0.x = f2bf(o0[rr * 4 + 0] * rl); p0.y = f2bf(o0[rr * 4 + 1] * rl);
    p0.z = f2bf(o0[rr * 4 + 2] * rl); p0.w = f2bf(o0[rr * 4 + 3] * rl);
    p1.x = f2bf(o1[rr * 4 + 0] * rl); p1.y = f2bf(o1[rr * 4 + 1] * rl);
    p1.z = f2bf(o1[rr * 4 + 2] * rl); p1.w = f2bf(o1[rr * 4 + 3] * rl);
    *(ushort4*)(dst + rr * 8 + 4 * h)      = p0;
    *(ushort4*)(dst + 32 + rr * 8 + 4 * h) = p1;
  }
}

// ---------------- launch ----------------
extern "C" void kernel_launch(void* const* d_in, const int* in_sizes, int n_in,
                              void* d_out, int out_size, void* d_ws, size_t ws_size,
                              hipStream_t stream)
{
  const float* q  = (const float*)d_in[0];
  const float* k  = (const float*)d_in[1];
  const float* v  = (const float*)d_in[2];
  const float* Wq = (const float*)d_in[3];
  const float* bq = (const float*)d_in[4];
  const float* Wk = (const float*)d_in[5];
  const float* bk = (const float*)d_in[6];
  const float* Wv = (const float*)d_in[7];
  const float* bv = (const float*)d_in[8];
  const float* Wo = (const float*)d_in[9];
  const float* bo = (const float*)d_in[10];

  char* ws = (char*)d_ws;
  size_t off = 0;
  auto alloc = [&](size_t bytes) -> void* {
    void* p = ws + off;
    off += (bytes + 255) & ~(size_t)255;
    return p;
  };
  unsigned short* Xq  = (unsigned short*)alloc(4194304ull * 2);
  unsigned short* Xk  = (unsigned short*)alloc(4194304ull * 2);
  unsigned short* Xv  = (unsigned short*)alloc(4194304ull * 2);
  unsigned short* Wqb = (unsigned short*)alloc(1048576ull * 2);
  unsigned short* Wkb = (unsigned short*)alloc(1048576ull * 2);
  unsigned short* Wvb = (unsigned short*)alloc(1048576ull * 2);
  unsigned short* Wob = (unsigned short*)alloc(1048576ull * 2);
  unsigned short* Qg  = (unsigned short*)alloc(4194304ull * 2);
  unsigned short* Kg  = (unsigned short*)alloc(4194304ull * 2);
  unsigned short* Vtb = (unsigned short*)alloc(4194304ull * 2);
  unsigned short* aOg = (unsigned short*)alloc(4194304ull * 2);
  float2*         rtab = (float2*)alloc(2048ull * 32 * 8);

  ConvArgs ca;
  const float* srcs[7] = {q, k, v, Wq, Wk, Wv, Wo};
  unsigned short* dsts[7] = {Xq, Xk, Xv, Wqb, Wkb, Wvb, Wob};
  int ns[7] = {4194304, 4194304, 4194304, 1048576, 1048576, 1048576, 1048576};
  for (int i = 0; i < 7; i++){ ca.src[i] = srcs[i]; ca.dst[i] = dsts[i]; ca.n[i] = ns[i]; }
  ca.rtab = rtab;

  conv_kernel<<<dim3(4096, 8), 256, 0, stream>>>(ca);
  gemm_qkv<<<dim3(32, 16, 3), 256, 0, stream>>>(Xq, Xk, Xv, Wqb, Wkb, Wvb, bq, bk, bv, Qg, Kg, Vtb, rtab);
  attn_kernel<<<dim3(512), 256, 0, stream>>>(Qg, Kg, Vtb, aOg);
  gemm_o<<<dim3(64, 16), 256, 0, stream>>>(aOg, Wob, bo, (float*)d_out);
}